// Round 1
// baseline (1207.060 us; speedup 1.0000x reference)
//
#include <hip/hip_runtime.h>
#include <hip/hip_bf16.h>

#define N_NODES 100000
#define N_EDGES 1600000
#define DD 128
#define EPS_BN 1e-5f
#define EPS_LN 1e-5f
#define SCAN_B 1024
#define NBLK 98  // ceil(100000/1024)

typedef __attribute__((ext_vector_type(4))) float floatx4;
typedef __attribute__((ext_vector_type(8))) short short8;
typedef __attribute__((ext_vector_type(4))) short short4v;

__device__ inline short f2bf(float f) {
  unsigned u = __builtin_bit_cast(unsigned, f);
  unsigned r = (u + 0x7FFFu + ((u >> 16) & 1u)) >> 16;
  return (short)r;
}

// ---------------- edge-index dtype detection (int32 vs int64 storage) -------
__global__ __launch_bounds__(1024) void detect_kernel(const int* __restrict__ ei,
                                                      int* __restrict__ flag) {
  __shared__ int nz;
  if (threadIdx.x == 0) nz = 0;
  __syncthreads();
  int v = ei[threadIdx.x * 2 + 1];  // if int64 storage: high words of first 1024 rows == 0
  if (v != 0) atomicAdd(&nz, 1);
  __syncthreads();
  if (threadIdx.x == 0) flag[0] = (nz == 0) ? 1 : 0;
}

__device__ inline int edge_row(const int* ei, int e, int f) {
  return f ? ei[2 * e] : ei[e];
}
__device__ inline int edge_col(const int* ei, int e, int f) {
  return f ? ei[2 * (N_EDGES + e)] : ei[N_EDGES + e];
}

// ---------------- precompute: degree count, dinv, CSR build -----------------
__global__ void init_kernel(int* __restrict__ cnt, float* __restrict__ sums) {
  int i = blockIdx.x * blockDim.x + threadIdx.x;
  if (i < N_NODES) cnt[i] = 0;
  if (i < 512) sums[i] = 0.f;
}

__global__ void count_kernel(const int* __restrict__ ei, const int* __restrict__ flag,
                             int* __restrict__ cnt) {
  int e = blockIdx.x * blockDim.x + threadIdx.x;
  if (e < N_EDGES) atomicAdd(&cnt[edge_col(ei, e, flag[0])], 1);
}

__global__ void dinv_kernel(const int* __restrict__ cnt, float* __restrict__ dinv,
                            float* __restrict__ d2) {
  int i = blockIdx.x * blockDim.x + threadIdx.x;
  if (i < N_NODES) {
    float dv = rsqrtf((float)cnt[i] + 1.0f);
    dinv[i] = dv;
    d2[i] = dv * dv;
  }
}

__global__ __launch_bounds__(1024) void scan_block_kernel(const int* __restrict__ cnt,
                                                          int* __restrict__ off,
                                                          int* __restrict__ blksum) {
  __shared__ int tmp[SCAN_B];
  int tid = threadIdx.x;
  int gid = blockIdx.x * SCAN_B + tid;
  int v = (gid < N_NODES) ? cnt[gid] : 0;
  tmp[tid] = v;
  __syncthreads();
  for (int o = 1; o < SCAN_B; o <<= 1) {
    int t = (tid >= o) ? tmp[tid - o] : 0;
    __syncthreads();
    tmp[tid] += t;
    __syncthreads();
  }
  if (gid < N_NODES) off[gid] = tmp[tid] - v;  // exclusive
  if (tid == SCAN_B - 1) blksum[blockIdx.x] = tmp[tid];
}

__global__ __launch_bounds__(1024) void scan_tops_kernel(int* __restrict__ blksum) {
  __shared__ int tmp[SCAN_B];
  int tid = threadIdx.x;
  int v = (tid < NBLK) ? blksum[tid] : 0;
  tmp[tid] = v;
  __syncthreads();
  for (int o = 1; o < SCAN_B; o <<= 1) {
    int t = (tid >= o) ? tmp[tid - o] : 0;
    __syncthreads();
    tmp[tid] += t;
    __syncthreads();
  }
  if (tid < NBLK) blksum[tid] = tmp[tid] - v;
}

__global__ __launch_bounds__(1024) void scan_add_kernel(int* __restrict__ off,
                                                        int* __restrict__ fillpos,
                                                        const int* __restrict__ blksum) {
  int gid = blockIdx.x * SCAN_B + threadIdx.x;
  if (gid < N_NODES) {
    int o = off[gid] + blksum[blockIdx.x];
    off[gid] = o;
    fillpos[gid] = o;
  }
  if (gid == 0) off[N_NODES] = N_EDGES;
}

__global__ void fill_kernel(const int* __restrict__ ei, const int* __restrict__ flag,
                            const float* __restrict__ dinv, int* __restrict__ fillpos,
                            int* __restrict__ esrc, float* __restrict__ ew) {
  int e = blockIdx.x * blockDim.x + threadIdx.x;
  if (e >= N_EDGES) return;
  int f = flag[0];
  int r = edge_row(ei, e, f);
  int c = edge_col(ei, e, f);
  int p = atomicAdd(&fillpos[c], 1);
  esrc[p] = r;
  ew[p] = dinv[r] * dinv[c];
}

// ---------------- weight prep: fp32 [in][out] -> bf16 transposed [out][in] --
__global__ void prep_w_kernel(const float* __restrict__ W0, const float* __restrict__ W1,
                              const float* __restrict__ W2, const float* __restrict__ Wv,
                              const float* __restrict__ Wo, short* __restrict__ Wt) {
  int id = blockIdx.x * blockDim.x + threadIdx.x;
  if (id >= 5 * DD * DD) return;
  int mat = id / (DD * DD);
  int rem = id % (DD * DD);
  int k = rem / DD;  // in
  int n = rem % DD;  // out
  const float* W = (mat == 0) ? W0 : (mat == 1) ? W1 : (mat == 2) ? W2 : (mat == 3) ? Wv : Wo;
  Wt[mat * DD * DD + n * DD + k] = f2bf(W[k * DD + n]);
}

// ---------------- bf16 MFMA GEMM: C[N,128] = A[N,128] @ W[128,128] (+bias)(+res)
__global__ __launch_bounds__(256) void gemm_bf16_kernel(const float* __restrict__ A,
                                                        const short* __restrict__ Wt,
                                                        const float* __restrict__ bias,
                                                        const float* __restrict__ res,
                                                        float* __restrict__ C) {
  __shared__ short As[128][136];  // +8 pad: breaks 16-way bank conflict on frag reads
  __shared__ short Ws[128][136];
  const int tid = threadIdx.x;
  const int rowbase = blockIdx.x * 128;

  // stage Wt (bf16 [out][in]) into LDS
#pragma unroll
  for (int i = 0; i < 8; ++i) {
    int ch = tid + i * 256;  // 2048 chunks of 8 shorts
    int r = ch >> 4;
    int c = (ch & 15) << 3;
    int4 v = *(const int4*)(Wt + r * DD + c);
    *(int4*)(&Ws[r][c]) = v;
  }
  // stage A tile (fp32 -> bf16)
#pragma unroll
  for (int i = 0; i < 16; ++i) {
    int ch = tid + i * 256;  // 4096 chunks of 4 floats
    int r = ch >> 5;
    int c = (ch & 31) << 2;
    int row = rowbase + r;
    float4 v = make_float4(0.f, 0.f, 0.f, 0.f);
    if (row < N_NODES) v = *(const float4*)(A + row * DD + c);
    short4v s;
    s.x = f2bf(v.x);
    s.y = f2bf(v.y);
    s.z = f2bf(v.z);
    s.w = f2bf(v.w);
    *(short4v*)(&As[r][c]) = s;
  }
  __syncthreads();

  const int lane = tid & 63;
  const int wv = tid >> 6;
  const int m = lane & 15;
  const int q = lane >> 4;
  const int r0 = wv * 32;

  floatx4 acc[2][8];
#pragma unroll
  for (int t = 0; t < 2; ++t)
#pragma unroll
    for (int n = 0; n < 8; ++n) acc[t][n] = (floatx4){0.f, 0.f, 0.f, 0.f};

#pragma unroll
  for (int kc = 0; kc < 4; ++kc) {
    int k = kc * 32 + q * 8;
    short8 a0 = *(const short8*)(&As[r0 + m][k]);
    short8 a1 = *(const short8*)(&As[r0 + 16 + m][k]);
#pragma unroll
    for (int n = 0; n < 8; ++n) {
      short8 b = *(const short8*)(&Ws[n * 16 + m][k]);
      acc[0][n] = __builtin_amdgcn_mfma_f32_16x16x32_bf16(a0, b, acc[0][n], 0, 0, 0);
      acc[1][n] = __builtin_amdgcn_mfma_f32_16x16x32_bf16(a1, b, acc[1][n], 0, 0, 0);
    }
  }

  // epilogue: C/D layout col=lane&15, row=(lane>>4)*4+reg [measured m89/m91]
#pragma unroll
  for (int t = 0; t < 2; ++t) {
#pragma unroll
    for (int n = 0; n < 8; ++n) {
      int col = n * 16 + m;
      float bvv = bias ? bias[col] : 0.f;
#pragma unroll
      for (int r = 0; r < 4; ++r) {
        int row = rowbase + r0 + t * 16 + q * 4 + r;
        if (row < N_NODES) {
          float v = acc[t][n][r] + bvv;
          if (res) v += res[row * DD + col];
          C[row * DD + col] = v;
        }
      }
    }
  }
}

// ---------------- sparse aggregate: out = sum_{e: col=n} w_e * hW[row_e] + d2[n]*hW[n] + b
__global__ __launch_bounds__(256) void aggregate_kernel(const float* __restrict__ hW,
                                                        const int* __restrict__ esrc,
                                                        const float* __restrict__ ew,
                                                        const int* __restrict__ off,
                                                        const float* __restrict__ d2,
                                                        const float* __restrict__ bias,
                                                        float* __restrict__ out) {
  int node = (blockIdx.x * blockDim.x + threadIdx.x) >> 6;
  int lane = threadIdx.x & 63;
  if (node >= N_NODES) return;
  int s = off[node], e = off[node + 1];
  const float2* hw2 = (const float2*)hW;
  float2 acc = make_float2(0.f, 0.f);
  for (int p = s; p < e; ++p) {
    int src = esrc[p];
    float w = ew[p];
    float2 v = hw2[src * 64 + lane];
    acc.x += w * v.x;
    acc.y += w * v.y;
  }
  float sw = d2[node];
  float2 hv = hw2[node * 64 + lane];
  float2 b = ((const float2*)bias)[lane];
  float2 o;
  o.x = acc.x + sw * hv.x + b.x;
  o.y = acc.y + sw * hv.y + b.y;
  ((float2*)out)[node * 64 + lane] = o;
}

// ---------------- BN stats (per-feature sum, sumsq over nodes) --------------
__global__ void bn_stats_kernel(const float* __restrict__ in, float* __restrict__ sum,
                                float* __restrict__ sumsq) {
  int col = threadIdx.x;  // 128 threads
  float s = 0.f, ss = 0.f;
  for (int r = blockIdx.x; r < N_NODES; r += gridDim.x) {
    float v = in[r * DD + col];
    s += v;
    ss += v * v;
  }
  atomicAdd(&sum[col], s);
  atomicAdd(&sumsq[col], ss);
}

// ---------------- BN normalize + ReLU + residual ----------------------------
__global__ void bn_norm_kernel(const float* __restrict__ in, const float* __restrict__ sum,
                               const float* __restrict__ sumsq, const float* __restrict__ g,
                               const float* __restrict__ be, const float* __restrict__ res,
                               float* __restrict__ out) {
  int idx = blockIdx.x * blockDim.x + threadIdx.x;  // over N*32 float4 groups
  if (idx >= N_NODES * 32) return;
  int c4 = (idx & 31) << 2;
  float4 v = ((const float4*)in)[idx];
  float4 r = ((const float4*)res)[idx];
  float4 o;
  const float invn = 1.0f / (float)N_NODES;
#pragma unroll
  for (int j = 0; j < 4; ++j) {
    int c = c4 + j;
    float mu = sum[c] * invn;
    float var = sumsq[c] * invn - mu * mu;
    float sc = g[c] * rsqrtf(var + EPS_BN);
    float x = ((const float*)&v)[j];
    float y = (x - mu) * sc + be[c];
    y = fmaxf(y, 0.f);
    ((float*)&o)[j] = y + ((const float*)&r)[j];
  }
  ((float4*)out)[idx] = o;
}

// ---------------- row LayerNorm ---------------------------------------------
__global__ __launch_bounds__(256) void ln_kernel(const float* __restrict__ in,
                                                 const float* __restrict__ g,
                                                 const float* __restrict__ b,
                                                 float* __restrict__ out) {
  int node = (blockIdx.x * blockDim.x + threadIdx.x) >> 6;
  int lane = threadIdx.x & 63;
  if (node >= N_NODES) return;
  float2 v = ((const float2*)in)[node * 64 + lane];
  float s = v.x + v.y;
  float ss = v.x * v.x + v.y * v.y;
#pragma unroll
  for (int o = 32; o > 0; o >>= 1) {
    s += __shfl_xor(s, o, 64);
    ss += __shfl_xor(ss, o, 64);
  }
  float mu = s * (1.f / 128.f);
  float var = ss * (1.f / 128.f) - mu * mu;
  float rs = rsqrtf(var + EPS_LN);
  float2 gg = ((const float2*)g)[lane];
  float2 bb = ((const float2*)b)[lane];
  float2 o2;
  o2.x = (v.x - mu) * rs * gg.x + bb.x;
  o2.y = (v.y - mu) * rs * gg.y + bb.y;
  ((float2*)out)[node * 64 + lane] = o2;
}

extern "C" void kernel_launch(void* const* d_in, const int* in_sizes, int n_in,
                              void* d_out, int out_size, void* d_ws, size_t ws_size,
                              hipStream_t stream) {
  const float* x = (const float*)d_in[0];
  const int* ei = (const int*)d_in[1];
  const float* W0 = (const float*)d_in[2];
  const float* b0 = (const float*)d_in[3];
  const float* W1 = (const float*)d_in[4];
  const float* b1 = (const float*)d_in[5];
  const float* W2 = (const float*)d_in[6];
  const float* b2 = (const float*)d_in[7];
  const float* g0 = (const float*)d_in[8];
  const float* be0 = (const float*)d_in[9];
  const float* g1 = (const float*)d_in[10];
  const float* be1 = (const float*)d_in[11];
  const float* Wv = (const float*)d_in[12];
  const float* bv = (const float*)d_in[13];
  const float* Wo = (const float*)d_in[14];
  const float* bo = (const float*)d_in[15];
  const float* lng = (const float*)d_in[16];
  const float* lnb = (const float*)d_in[17];
  float* outp = (float*)d_out;

  char* w = (char*)d_ws;
  float* bufA = (float*)(w + 0);               // 51,200,000 B
  float* bufB = (float*)(w + 51200000);        // 51,200,000 B
  int* esrc = (int*)(w + 102400000);           // 6,400,000 B
  float* ewgt = (float*)(w + 108800000);       // 6,400,000 B
  int* cnt = (int*)(w + 115200000);            // 400,000 B
  int* off = (int*)(w + 115600000);            // 400,004 B (pad)
  int* fillpos = (int*)(w + 116000256);        // 400,000 B
  float* dinv = (float*)(w + 116400256);       // 400,000 B
  float* d2v = (float*)(w + 116800256);        // 400,000 B
  int* blksum = (int*)(w + 117200256);         // 512 B
  float* sums = (float*)(w + 117200768);       // 2048 B (sum0,sumsq0,sum1,sumsq1)
  short* Wt = (short*)(w + 117202816);         // 163,840 B
  int* flag = (int*)(w + 117366656);           // 4 B
  float* outC = outp;  // d_out doubles as third big buffer

  // --- precompute: edge dtype, degrees, CSR, weights ---
  detect_kernel<<<1, 1024, 0, stream>>>(ei, flag);
  init_kernel<<<(N_NODES + 255) / 256, 256, 0, stream>>>(cnt, sums);
  count_kernel<<<(N_EDGES + 255) / 256, 256, 0, stream>>>(ei, flag, cnt);
  dinv_kernel<<<(N_NODES + 255) / 256, 256, 0, stream>>>(cnt, dinv, d2v);
  scan_block_kernel<<<NBLK, SCAN_B, 0, stream>>>(cnt, off, blksum);
  scan_tops_kernel<<<1, SCAN_B, 0, stream>>>(blksum);
  scan_add_kernel<<<NBLK, SCAN_B, 0, stream>>>(off, fillpos, blksum);
  fill_kernel<<<(N_EDGES + 255) / 256, 256, 0, stream>>>(ei, flag, dinv, fillpos, esrc, ewgt);
  prep_w_kernel<<<(5 * DD * DD + 255) / 256, 256, 0, stream>>>(W0, W1, W2, Wv, Wo, Wt);

  const int GB = (N_NODES + 127) / 128;   // 782 gemm blocks
  const int AB = (N_NODES + 3) / 4;       // 25000 aggregate blocks (4 waves/block)
  const int EB = (N_NODES * 32 + 255) / 256;

  // --- layer 0: conv -> BN -> relu -> +x ---
  gemm_bf16_kernel<<<GB, 256, 0, stream>>>(x, Wt + 0 * DD * DD, nullptr, nullptr, bufA);
  aggregate_kernel<<<AB, 256, 0, stream>>>(bufA, esrc, ewgt, off, d2v, b0, bufB);
  bn_stats_kernel<<<512, 128, 0, stream>>>(bufB, sums + 0, sums + 128);
  bn_norm_kernel<<<EB, 256, 0, stream>>>(bufB, sums + 0, sums + 128, g0, be0, x, bufA);  // h1=bufA

  // --- layer 1 ---
  gemm_bf16_kernel<<<GB, 256, 0, stream>>>(bufA, Wt + 1 * DD * DD, nullptr, nullptr, bufB);
  aggregate_kernel<<<AB, 256, 0, stream>>>(bufB, esrc, ewgt, off, d2v, b1, outC);
  bn_stats_kernel<<<512, 128, 0, stream>>>(outC, sums + 256, sums + 384);
  bn_norm_kernel<<<EB, 256, 0, stream>>>(outC, sums + 256, sums + 384, g1, be1, bufA, bufB);  // h2=bufB

  // --- MHA (seq_len=1): att = (h2@Wv+bv)@Wo+bo ; h3 = LN(h2+att) ---
  gemm_bf16_kernel<<<GB, 256, 0, stream>>>(bufB, Wt + 3 * DD * DD, bv, nullptr, outC);       // v
  gemm_bf16_kernel<<<GB, 256, 0, stream>>>(outC, Wt + 4 * DD * DD, bo, bufB, bufA);          // t = h2+v@Wo+bo
  ln_kernel<<<AB, 256, 0, stream>>>(bufA, lng, lnb, outC);                                    // h3

  // --- output conv ---
  gemm_bf16_kernel<<<GB, 256, 0, stream>>>(outC, Wt + 2 * DD * DD, nullptr, nullptr, bufB);  // h3@W2
  aggregate_kernel<<<AB, 256, 0, stream>>>(bufB, esrc, ewgt, off, d2v, b2, outp);
}

// Round 2
// 782.898 us; speedup vs baseline: 1.5418x; 1.5418x over previous
//
#include <hip/hip_runtime.h>
#include <hip/hip_bf16.h>

#define N_NODES 100000
#define N_EDGES 1600000
#define DD 128
#define EPS_BN 1e-5f
#define EPS_LN 1e-5f
#define SCAN_B 1024
#define NBLK 98  // ceil(100000/1024)

typedef __attribute__((ext_vector_type(4))) float floatx4;
typedef __attribute__((ext_vector_type(8))) short short8;
typedef __attribute__((ext_vector_type(4))) short short4v;

__device__ inline unsigned short f2bf(float f) {
  unsigned u = __builtin_bit_cast(unsigned, f);
  unsigned r = (u + 0x7FFFu + ((u >> 16) & 1u)) >> 16;
  return (unsigned short)r;
}
__device__ inline float bf2f(unsigned short s) {
  unsigned u = ((unsigned)s) << 16;
  return __builtin_bit_cast(float, u);
}

// ---------------- edge-index dtype detection (int32 vs int64 storage) -------
__global__ __launch_bounds__(1024) void detect_kernel(const int* __restrict__ ei,
                                                      int* __restrict__ flag) {
  __shared__ int nz;
  if (threadIdx.x == 0) nz = 0;
  __syncthreads();
  int v = ei[threadIdx.x * 2 + 1];  // if int64 storage: high words of first 1024 rows == 0
  if (v != 0) atomicAdd(&nz, 1);
  __syncthreads();
  if (threadIdx.x == 0) flag[0] = (nz == 0) ? 1 : 0;
}

__device__ inline int edge_row(const int* ei, int e, int f) {
  return f ? ei[2 * e] : ei[e];
}
__device__ inline int edge_col(const int* ei, int e, int f) {
  return f ? ei[2 * (N_EDGES + e)] : ei[N_EDGES + e];
}

// ---------------- precompute: degree count, dinv, CSR build -----------------
__global__ void init_kernel(int* __restrict__ cnt, float* __restrict__ sums) {
  int i = blockIdx.x * blockDim.x + threadIdx.x;
  if (i < N_NODES) cnt[i] = 0;
  if (i < 512) sums[i] = 0.f;
}

__global__ void count_kernel(const int* __restrict__ ei, const int* __restrict__ flag,
                             int* __restrict__ cnt) {
  int e = blockIdx.x * blockDim.x + threadIdx.x;
  if (e < N_EDGES) atomicAdd(&cnt[edge_col(ei, e, flag[0])], 1);
}

__global__ void dinv_kernel(const int* __restrict__ cnt, float* __restrict__ dinv,
                            float* __restrict__ d2) {
  int i = blockIdx.x * blockDim.x + threadIdx.x;
  if (i < N_NODES) {
    float dv = rsqrtf((float)cnt[i] + 1.0f);
    dinv[i] = dv;
    d2[i] = dv * dv;
  }
}

__global__ __launch_bounds__(1024) void scan_block_kernel(const int* __restrict__ cnt,
                                                          int* __restrict__ off,
                                                          int* __restrict__ blksum) {
  __shared__ int tmp[SCAN_B];
  int tid = threadIdx.x;
  int gid = blockIdx.x * SCAN_B + tid;
  int v = (gid < N_NODES) ? cnt[gid] : 0;
  tmp[tid] = v;
  __syncthreads();
  for (int o = 1; o < SCAN_B; o <<= 1) {
    int t = (tid >= o) ? tmp[tid - o] : 0;
    __syncthreads();
    tmp[tid] += t;
    __syncthreads();
  }
  if (gid < N_NODES) off[gid] = tmp[tid] - v;  // exclusive
  if (tid == SCAN_B - 1) blksum[blockIdx.x] = tmp[tid];
}

__global__ __launch_bounds__(1024) void scan_tops_kernel(int* __restrict__ blksum) {
  __shared__ int tmp[SCAN_B];
  int tid = threadIdx.x;
  int v = (tid < NBLK) ? blksum[tid] : 0;
  tmp[tid] = v;
  __syncthreads();
  for (int o = 1; o < SCAN_B; o <<= 1) {
    int t = (tid >= o) ? tmp[tid - o] : 0;
    __syncthreads();
    tmp[tid] += t;
    __syncthreads();
  }
  if (tid < NBLK) blksum[tid] = tmp[tid] - v;
}

__global__ __launch_bounds__(1024) void scan_add_kernel(int* __restrict__ off,
                                                        int* __restrict__ fillpos,
                                                        const int* __restrict__ blksum) {
  int gid = blockIdx.x * SCAN_B + threadIdx.x;
  if (gid < N_NODES) {
    int o = off[gid] + blksum[blockIdx.x];
    off[gid] = o;
    fillpos[gid] = o;
  }
  if (gid == 0) off[N_NODES] = N_EDGES;
}

__global__ void fill_kernel(const int* __restrict__ ei, const int* __restrict__ flag,
                            const float* __restrict__ dinv, int* __restrict__ fillpos,
                            int* __restrict__ esrc, float* __restrict__ ew) {
  int e = blockIdx.x * blockDim.x + threadIdx.x;
  if (e >= N_EDGES) return;
  int f = flag[0];
  int r = edge_row(ei, e, f);
  int c = edge_col(ei, e, f);
  int p = atomicAdd(&fillpos[c], 1);
  esrc[p] = r;
  ew[p] = dinv[r] * dinv[c];
}

// ---------------- weight prep: fp32 [in][out] -> bf16 transposed [out][in] --
__global__ void prep_w_kernel(const float* __restrict__ W0, const float* __restrict__ W1,
                              const float* __restrict__ W2, const float* __restrict__ Wv,
                              const float* __restrict__ Wo, unsigned short* __restrict__ Wt) {
  int id = blockIdx.x * blockDim.x + threadIdx.x;
  if (id >= 5 * DD * DD) return;
  int mat = id / (DD * DD);
  int rem = id % (DD * DD);
  int k = rem / DD;  // in
  int n = rem % DD;  // out
  const float* W = (mat == 0) ? W0 : (mat == 1) ? W1 : (mat == 2) ? W2 : (mat == 3) ? Wv : Wo;
  Wt[mat * DD * DD + n * DD + k] = f2bf(W[k * DD + n]);
}

// ---------------- bf16 MFMA GEMM -> bf16 C:  C[N,128] = A[N,128] @ W (+bias)
// AT = float (converts) or unsigned short (bf16 passthrough)
template <typename AT>
__global__ __launch_bounds__(256) void gemm_bf16_kernel(const AT* __restrict__ A,
                                                        const unsigned short* __restrict__ Wt,
                                                        const float* __restrict__ bias,
                                                        unsigned short* __restrict__ C) {
  __shared__ short As[128][136];  // +8 pad: breaks bank conflicts on frag reads
  __shared__ short Ws[128][136];
  const int tid = threadIdx.x;
  const int rowbase = blockIdx.x * 128;

  // stage Wt (bf16 [out][in]) into LDS
#pragma unroll
  for (int i = 0; i < 8; ++i) {
    int ch = tid + i * 256;  // 2048 chunks of 8 shorts
    int r = ch >> 4;
    int c = (ch & 15) << 3;
    int4 v = *(const int4*)(Wt + r * DD + c);
    *(int4*)(&Ws[r][c]) = v;
  }
  // stage A tile
  if constexpr (__is_same(AT, float)) {
#pragma unroll
    for (int i = 0; i < 16; ++i) {
      int ch = tid + i * 256;  // 4096 chunks of 4 floats
      int r = ch >> 5;
      int c = (ch & 31) << 2;
      int row = rowbase + r;
      float4 v = make_float4(0.f, 0.f, 0.f, 0.f);
      if (row < N_NODES) v = *(const float4*)(A + row * DD + c);
      short4v s;
      s.x = f2bf(v.x);
      s.y = f2bf(v.y);
      s.z = f2bf(v.z);
      s.w = f2bf(v.w);
      *(short4v*)(&As[r][c]) = s;
    }
  } else {
#pragma unroll
    for (int i = 0; i < 8; ++i) {
      int ch = tid + i * 256;  // 2048 chunks of 8 shorts
      int r = ch >> 4;
      int c = (ch & 15) << 3;
      int row = rowbase + r;
      int4 v = make_int4(0, 0, 0, 0);
      if (row < N_NODES) v = *(const int4*)(A + row * DD + c);
      *(int4*)(&As[r][c]) = v;
    }
  }
  __syncthreads();

  const int lane = tid & 63;
  const int wv = tid >> 6;
  const int m = lane & 15;
  const int q = lane >> 4;
  const int r0 = wv * 32;

  floatx4 acc[2][8];
#pragma unroll
  for (int t = 0; t < 2; ++t)
#pragma unroll
    for (int n = 0; n < 8; ++n) acc[t][n] = (floatx4){0.f, 0.f, 0.f, 0.f};

#pragma unroll
  for (int kc = 0; kc < 4; ++kc) {
    int k = kc * 32 + q * 8;
    short8 a0 = *(const short8*)(&As[r0 + m][k]);
    short8 a1 = *(const short8*)(&As[r0 + 16 + m][k]);
#pragma unroll
    for (int n = 0; n < 8; ++n) {
      short8 b = *(const short8*)(&Ws[n * 16 + m][k]);
      acc[0][n] = __builtin_amdgcn_mfma_f32_16x16x32_bf16(a0, b, acc[0][n], 0, 0, 0);
      acc[1][n] = __builtin_amdgcn_mfma_f32_16x16x32_bf16(a1, b, acc[1][n], 0, 0, 0);
    }
  }

  // epilogue: stage bf16 C tile in LDS (reuse As), then coalesced 16B stores.
  // C/D layout col=lane&15, row=(lane>>4)*4+reg [measured m89/m91]
  __syncthreads();
#pragma unroll
  for (int n = 0; n < 8; ++n) {
    int col = n * 16 + m;
    float bvv = bias ? bias[col] : 0.f;
#pragma unroll
    for (int t = 0; t < 2; ++t) {
#pragma unroll
      for (int r = 0; r < 4; ++r) {
        int rl = r0 + t * 16 + q * 4 + r;
        As[rl][col] = (short)f2bf(acc[t][n][r] + bvv);
      }
    }
  }
  __syncthreads();
#pragma unroll
  for (int i = 0; i < 8; ++i) {
    int ch = tid + i * 256;
    int r = ch >> 4;
    int c = (ch & 15) << 3;
    int row = rowbase + r;
    if (row < N_NODES) *(int4*)(C + row * DD + c) = *(const int4*)(&As[r][c]);
  }
}

// ---------------- bf16 MFMA GEMM -> fp32 C with bf16 residual (MHA out proj)
__global__ __launch_bounds__(256) void gemm_f32res_kernel(const unsigned short* __restrict__ A,
                                                          const unsigned short* __restrict__ Wt,
                                                          const float* __restrict__ bias,
                                                          const unsigned short* __restrict__ res,
                                                          float* __restrict__ C) {
  __shared__ short As[128][136];
  __shared__ short Ws[128][136];
  const int tid = threadIdx.x;
  const int rowbase = blockIdx.x * 128;

#pragma unroll
  for (int i = 0; i < 8; ++i) {
    int ch = tid + i * 256;
    int r = ch >> 4;
    int c = (ch & 15) << 3;
    int4 v = *(const int4*)(Wt + r * DD + c);
    *(int4*)(&Ws[r][c]) = v;
  }
#pragma unroll
  for (int i = 0; i < 8; ++i) {
    int ch = tid + i * 256;
    int r = ch >> 4;
    int c = (ch & 15) << 3;
    int row = rowbase + r;
    int4 v = make_int4(0, 0, 0, 0);
    if (row < N_NODES) v = *(const int4*)(A + row * DD + c);
    *(int4*)(&As[r][c]) = v;
  }
  __syncthreads();

  const int lane = tid & 63;
  const int wv = tid >> 6;
  const int m = lane & 15;
  const int q = lane >> 4;
  const int r0 = wv * 32;

  floatx4 acc[2][8];
#pragma unroll
  for (int t = 0; t < 2; ++t)
#pragma unroll
    for (int n = 0; n < 8; ++n) acc[t][n] = (floatx4){0.f, 0.f, 0.f, 0.f};

#pragma unroll
  for (int kc = 0; kc < 4; ++kc) {
    int k = kc * 32 + q * 8;
    short8 a0 = *(const short8*)(&As[r0 + m][k]);
    short8 a1 = *(const short8*)(&As[r0 + 16 + m][k]);
#pragma unroll
    for (int n = 0; n < 8; ++n) {
      short8 b = *(const short8*)(&Ws[n * 16 + m][k]);
      acc[0][n] = __builtin_amdgcn_mfma_f32_16x16x32_bf16(a0, b, acc[0][n], 0, 0, 0);
      acc[1][n] = __builtin_amdgcn_mfma_f32_16x16x32_bf16(a1, b, acc[1][n], 0, 0, 0);
    }
  }

#pragma unroll
  for (int t = 0; t < 2; ++t) {
#pragma unroll
    for (int n = 0; n < 8; ++n) {
      int col = n * 16 + m;
      float bvv = bias[col];
#pragma unroll
      for (int r = 0; r < 4; ++r) {
        int row = rowbase + r0 + t * 16 + q * 4 + r;
        if (row < N_NODES) {
          C[row * DD + col] = acc[t][n][r] + bvv + bf2f(res[row * DD + col]);
        }
      }
    }
  }
}

// ---------------- sparse aggregate (bf16 gather, fp32 out) ------------------
// out[n] = sum_{e: col=n} w_e * hW[row_e] + d2[n]*hW[n] + b
__global__ __launch_bounds__(256) void aggregate_kernel(const unsigned* __restrict__ hw,
                                                        const int* __restrict__ esrc,
                                                        const float* __restrict__ ew,
                                                        const int* __restrict__ off,
                                                        const float* __restrict__ d2,
                                                        const float* __restrict__ bias,
                                                        float* __restrict__ out) {
  int node = (blockIdx.x * blockDim.x + threadIdx.x) >> 6;
  int lane = threadIdx.x & 63;
  if (node >= N_NODES) return;
  node = __builtin_amdgcn_readfirstlane(node);  // force scalar edge-list walk
  int s = off[node], e = off[node + 1];
  float ax = 0.f, ay = 0.f;
  int p = s;
  for (; p + 3 < e; p += 4) {  // 4 outstanding gathers per wave
    int s0 = esrc[p], s1 = esrc[p + 1], s2 = esrc[p + 2], s3 = esrc[p + 3];
    float w0 = ew[p], w1 = ew[p + 1], w2 = ew[p + 2], w3 = ew[p + 3];
    unsigned u0 = hw[s0 * 64 + lane];
    unsigned u1 = hw[s1 * 64 + lane];
    unsigned u2 = hw[s2 * 64 + lane];
    unsigned u3 = hw[s3 * 64 + lane];
    ax += w0 * __builtin_bit_cast(float, u0 << 16);
    ay += w0 * __builtin_bit_cast(float, u0 & 0xFFFF0000u);
    ax += w1 * __builtin_bit_cast(float, u1 << 16);
    ay += w1 * __builtin_bit_cast(float, u1 & 0xFFFF0000u);
    ax += w2 * __builtin_bit_cast(float, u2 << 16);
    ay += w2 * __builtin_bit_cast(float, u2 & 0xFFFF0000u);
    ax += w3 * __builtin_bit_cast(float, u3 << 16);
    ay += w3 * __builtin_bit_cast(float, u3 & 0xFFFF0000u);
  }
  for (; p < e; ++p) {
    int src = esrc[p];
    float w = ew[p];
    unsigned u = hw[src * 64 + lane];
    ax += w * __builtin_bit_cast(float, u << 16);
    ay += w * __builtin_bit_cast(float, u & 0xFFFF0000u);
  }
  float sw = d2[node];
  unsigned uh = hw[node * 64 + lane];
  float2 b = ((const float2*)bias)[lane];
  float2 o;
  o.x = ax + sw * __builtin_bit_cast(float, uh << 16) + b.x;
  o.y = ay + sw * __builtin_bit_cast(float, uh & 0xFFFF0000u) + b.y;
  ((float2*)out)[node * 64 + lane] = o;
}

// ---------------- BN stats (per-feature sum, sumsq over nodes) --------------
__global__ void bn_stats_kernel(const float* __restrict__ in, float* __restrict__ sum,
                                float* __restrict__ sumsq) {
  int col = threadIdx.x;  // 128 threads
  float s = 0.f, ss = 0.f;
  for (int r = blockIdx.x; r < N_NODES; r += gridDim.x) {
    float v = in[r * DD + col];
    s += v;
    ss += v * v;
  }
  atomicAdd(&sum[col], s);
  atomicAdd(&sumsq[col], ss);
}

// ---------------- BN normalize + ReLU + residual -> bf16 --------------------
template <typename RT>
__global__ void bn_norm_kernel(const float* __restrict__ in, const float* __restrict__ sum,
                               const float* __restrict__ sumsq, const float* __restrict__ g,
                               const float* __restrict__ be, const RT* __restrict__ res,
                               unsigned short* __restrict__ out) {
  int idx = blockIdx.x * blockDim.x + threadIdx.x;  // over N*32 groups of 4 cols
  if (idx >= N_NODES * 32) return;
  int c4 = (idx & 31) << 2;
  float4 v = ((const float4*)in)[idx];
  float r4[4];
  if constexpr (__is_same(RT, float)) {
    float4 r = ((const float4*)res)[idx];
    r4[0] = r.x; r4[1] = r.y; r4[2] = r.z; r4[3] = r.w;
  } else {
    short4v r = ((const short4v*)res)[idx];
    r4[0] = bf2f((unsigned short)r.x);
    r4[1] = bf2f((unsigned short)r.y);
    r4[2] = bf2f((unsigned short)r.z);
    r4[3] = bf2f((unsigned short)r.w);
  }
  const float invn = 1.0f / (float)N_NODES;
  short4v o;
#pragma unroll
  for (int j = 0; j < 4; ++j) {
    int c = c4 + j;
    float mu = sum[c] * invn;
    float var = sumsq[c] * invn - mu * mu;
    float sc = g[c] * rsqrtf(var + EPS_BN);
    float x = ((const float*)&v)[j];
    float y = (x - mu) * sc + be[c];
    y = fmaxf(y, 0.f) + r4[j];
    ((short*)&o)[j] = (short)f2bf(y);
  }
  ((short4v*)out)[idx] = o;
}

// ---------------- row LayerNorm (fp32 in -> bf16 out) -----------------------
__global__ __launch_bounds__(256) void ln_kernel(const float* __restrict__ in,
                                                 const float* __restrict__ g,
                                                 const float* __restrict__ b,
                                                 unsigned* __restrict__ out) {
  int node = (blockIdx.x * blockDim.x + threadIdx.x) >> 6;
  int lane = threadIdx.x & 63;
  if (node >= N_NODES) return;
  float2 v = ((const float2*)in)[node * 64 + lane];
  float s = v.x + v.y;
  float ss = v.x * v.x + v.y * v.y;
#pragma unroll
  for (int o = 32; o > 0; o >>= 1) {
    s += __shfl_xor(s, o, 64);
    ss += __shfl_xor(ss, o, 64);
  }
  float mu = s * (1.f / 128.f);
  float var = ss * (1.f / 128.f) - mu * mu;
  float rs = rsqrtf(var + EPS_LN);
  float2 gg = ((const float2*)g)[lane];
  float2 bb = ((const float2*)b)[lane];
  float ox = (v.x - mu) * rs * gg.x + bb.x;
  float oy = (v.y - mu) * rs * gg.y + bb.y;
  out[node * 64 + lane] = (unsigned)f2bf(ox) | ((unsigned)f2bf(oy) << 16);
}

extern "C" void kernel_launch(void* const* d_in, const int* in_sizes, int n_in,
                              void* d_out, int out_size, void* d_ws, size_t ws_size,
                              hipStream_t stream) {
  const float* x = (const float*)d_in[0];
  const int* ei = (const int*)d_in[1];
  const float* W0 = (const float*)d_in[2];
  const float* b0 = (const float*)d_in[3];
  const float* W1 = (const float*)d_in[4];
  const float* b1 = (const float*)d_in[5];
  const float* W2 = (const float*)d_in[6];
  const float* b2 = (const float*)d_in[7];
  const float* g0 = (const float*)d_in[8];
  const float* be0 = (const float*)d_in[9];
  const float* g1 = (const float*)d_in[10];
  const float* be1 = (const float*)d_in[11];
  const float* Wv = (const float*)d_in[12];
  const float* bv = (const float*)d_in[13];
  const float* Wo = (const float*)d_in[14];
  const float* bo = (const float*)d_in[15];
  const float* lng = (const float*)d_in[16];
  const float* lnb = (const float*)d_in[17];
  float* outp = (float*)d_out;

  char* w = (char*)d_ws;
  unsigned short* Gb = (unsigned short*)(w + 0);          // 25,600,000 B (hW / V)
  unsigned short* h1b = (unsigned short*)(w + 25600000);  // 25,600,000 B (h1, later h3)
  unsigned short* h2b = (unsigned short*)(w + 51200000);  // 25,600,000 B (h2)
  int* esrc = (int*)(w + 76800000);                       // 6,400,000 B
  float* ewgt = (float*)(w + 83200000);                   // 6,400,000 B
  int* cnt = (int*)(w + 89600000);                        // 400,000 B
  int* off = (int*)(w + 90000000);                        // 400,004 B (pad)
  int* fillpos = (int*)(w + 90400256);                    // 400,000 B
  float* dinv = (float*)(w + 90800256);                   // 400,000 B
  float* d2v = (float*)(w + 91200256);                    // 400,000 B
  int* blksum = (int*)(w + 91600256);                     // 512 B
  float* sums = (float*)(w + 91600768);                   // 2048 B
  unsigned short* Wt = (unsigned short*)(w + 91602816);   // 163,840 B
  int* flag = (int*)(w + 91766656);                       // 4 B
  float* outF = outp;  // d_out doubles as the fp32 scratch (aggregate out / T)

  // --- precompute: edge dtype, degrees, CSR, weights ---
  detect_kernel<<<1, 1024, 0, stream>>>(ei, flag);
  init_kernel<<<(N_NODES + 255) / 256, 256, 0, stream>>>(cnt, sums);
  count_kernel<<<(N_EDGES + 255) / 256, 256, 0, stream>>>(ei, flag, cnt);
  dinv_kernel<<<(N_NODES + 255) / 256, 256, 0, stream>>>(cnt, dinv, d2v);
  scan_block_kernel<<<NBLK, SCAN_B, 0, stream>>>(cnt, off, blksum);
  scan_tops_kernel<<<1, SCAN_B, 0, stream>>>(blksum);
  scan_add_kernel<<<NBLK, SCAN_B, 0, stream>>>(off, fillpos, blksum);
  fill_kernel<<<(N_EDGES + 255) / 256, 256, 0, stream>>>(ei, flag, dinv, fillpos, esrc, ewgt);
  prep_w_kernel<<<(5 * DD * DD + 255) / 256, 256, 0, stream>>>(W0, W1, W2, Wv, Wo, Wt);

  const int GB = (N_NODES + 127) / 128;  // 782 gemm blocks
  const int AB = (N_NODES + 3) / 4;      // 25000 blocks (4 waves/block, 1 wave/node)
  const int EB = (N_NODES * 32 + 255) / 256;

  // --- layer 0: conv -> BN -> relu -> +x ---
  gemm_bf16_kernel<float><<<GB, 256, 0, stream>>>(x, Wt + 0 * DD * DD, nullptr, Gb);
  aggregate_kernel<<<AB, 256, 0, stream>>>((const unsigned*)Gb, esrc, ewgt, off, d2v, b0, outF);
  bn_stats_kernel<<<512, 128, 0, stream>>>(outF, sums + 0, sums + 128);
  bn_norm_kernel<float><<<EB, 256, 0, stream>>>(outF, sums + 0, sums + 128, g0, be0, x, h1b);

  // --- layer 1 ---
  gemm_bf16_kernel<unsigned short><<<GB, 256, 0, stream>>>(h1b, Wt + 1 * DD * DD, nullptr, Gb);
  aggregate_kernel<<<AB, 256, 0, stream>>>((const unsigned*)Gb, esrc, ewgt, off, d2v, b1, outF);
  bn_stats_kernel<<<512, 128, 0, stream>>>(outF, sums + 256, sums + 384);
  bn_norm_kernel<unsigned short><<<EB, 256, 0, stream>>>(outF, sums + 256, sums + 384, g1, be1,
                                                         h1b, h2b);

  // --- MHA (seq_len=1): att = (h2@Wv+bv)@Wo+bo ; h3 = LN(h2+att) ---
  gemm_bf16_kernel<unsigned short><<<GB, 256, 0, stream>>>(h2b, Wt + 3 * DD * DD, bv, Gb);  // V
  gemm_f32res_kernel<<<GB, 256, 0, stream>>>(Gb, Wt + 4 * DD * DD, bo, h2b, outF);          // T
  ln_kernel<<<AB, 256, 0, stream>>>(outF, lng, lnb, (unsigned*)h1b);                        // h3

  // --- output conv ---
  gemm_bf16_kernel<unsigned short><<<GB, 256, 0, stream>>>(h1b, Wt + 2 * DD * DD, nullptr, Gb);
  aggregate_kernel<<<AB, 256, 0, stream>>>((const unsigned*)Gb, esrc, ewgt, off, d2v, b2, outp);
}

// Round 3
// 707.942 us; speedup vs baseline: 1.7050x; 1.1059x over previous
//
#include <hip/hip_runtime.h>
#include <hip/hip_bf16.h>

#define N_NODES 100000
#define N_EDGES 1600000
#define DD 128
#define EPS_BN 1e-5f
#define EPS_LN 1e-5f
#define SCAN_B 1024
#define NBLK 98  // ceil(100000/1024)

typedef __attribute__((ext_vector_type(4))) float floatx4;
typedef __attribute__((ext_vector_type(8))) short short8;
typedef __attribute__((ext_vector_type(4))) short short4v;

__device__ inline unsigned short f2bf(float f) {
  unsigned u = __builtin_bit_cast(unsigned, f);
  unsigned r = (u + 0x7FFFu + ((u >> 16) & 1u)) >> 16;
  return (unsigned short)r;
}
__device__ inline float bf2f(unsigned short s) {
  unsigned u = ((unsigned)s) << 16;
  return __builtin_bit_cast(float, u);
}
__device__ inline float bflo(unsigned u) { return __builtin_bit_cast(float, u << 16); }
__device__ inline float bfhi(unsigned u) {
  return __builtin_bit_cast(float, u & 0xFFFF0000u);
}

// ---------------- edge-index dtype detection (int32 vs int64 storage) -------
__global__ __launch_bounds__(1024) void detect_kernel(const int* __restrict__ ei,
                                                      int* __restrict__ flag) {
  __shared__ int nz;
  if (threadIdx.x == 0) nz = 0;
  __syncthreads();
  int v = ei[threadIdx.x * 2 + 1];  // if int64 storage: high words of first 1024 rows == 0
  if (v != 0) atomicAdd(&nz, 1);
  __syncthreads();
  if (threadIdx.x == 0) flag[0] = (nz == 0) ? 1 : 0;
}

__device__ inline int edge_row(const int* ei, int e, int f) {
  return f ? ei[2 * e] : ei[e];
}
__device__ inline int edge_col(const int* ei, int e, int f) {
  return f ? ei[2 * (N_EDGES + e)] : ei[N_EDGES + e];
}

// ---------------- precompute: degree count, dinv, CSR build -----------------
__global__ void init_kernel(int* __restrict__ cnt, float* __restrict__ sums) {
  int i = blockIdx.x * blockDim.x + threadIdx.x;
  if (i < N_NODES) cnt[i] = 0;
  if (i < 512) sums[i] = 0.f;
}

__global__ void count_kernel(const int* __restrict__ ei, const int* __restrict__ flag,
                             int* __restrict__ cnt) {
  int e = blockIdx.x * blockDim.x + threadIdx.x;
  if (e < N_EDGES) atomicAdd(&cnt[edge_col(ei, e, flag[0])], 1);
}

__global__ void dinv_kernel(const int* __restrict__ cnt, float* __restrict__ dinv,
                            float* __restrict__ d2) {
  int i = blockIdx.x * blockDim.x + threadIdx.x;
  if (i < N_NODES) {
    float dv = rsqrtf((float)cnt[i] + 1.0f);
    dinv[i] = dv;
    d2[i] = dv * dv;
  }
}

__global__ __launch_bounds__(1024) void scan_block_kernel(const int* __restrict__ cnt,
                                                          int* __restrict__ off,
                                                          int* __restrict__ blksum) {
  __shared__ int tmp[SCAN_B];
  int tid = threadIdx.x;
  int gid = blockIdx.x * SCAN_B + tid;
  int v = (gid < N_NODES) ? cnt[gid] : 0;
  tmp[tid] = v;
  __syncthreads();
  for (int o = 1; o < SCAN_B; o <<= 1) {
    int t = (tid >= o) ? tmp[tid - o] : 0;
    __syncthreads();
    tmp[tid] += t;
    __syncthreads();
  }
  if (gid < N_NODES) off[gid] = tmp[tid] - v;  // exclusive
  if (tid == SCAN_B - 1) blksum[blockIdx.x] = tmp[tid];
}

__global__ __launch_bounds__(1024) void scan_tops_kernel(int* __restrict__ blksum) {
  __shared__ int tmp[SCAN_B];
  int tid = threadIdx.x;
  int v = (tid < NBLK) ? blksum[tid] : 0;
  tmp[tid] = v;
  __syncthreads();
  for (int o = 1; o < SCAN_B; o <<= 1) {
    int t = (tid >= o) ? tmp[tid - o] : 0;
    __syncthreads();
    tmp[tid] += t;
    __syncthreads();
  }
  if (tid < NBLK) blksum[tid] = tmp[tid] - v;
}

__global__ __launch_bounds__(1024) void scan_add_kernel(int* __restrict__ off,
                                                        int* __restrict__ fillpos,
                                                        const int* __restrict__ blksum) {
  int gid = blockIdx.x * SCAN_B + threadIdx.x;
  if (gid < N_NODES) {
    int o = off[gid] + blksum[blockIdx.x];
    off[gid] = o;
    fillpos[gid] = o;
  }
  if (gid == 0) off[N_NODES] = N_EDGES;
}

// fill: ONE 8B scattered store per edge (src idx + precomputed weight packed)
__global__ void fill_kernel(const int* __restrict__ ei, const int* __restrict__ flag,
                            const float* __restrict__ dinv, int* __restrict__ fillpos,
                            int2* __restrict__ ep) {
  int e = blockIdx.x * blockDim.x + threadIdx.x;
  if (e >= N_EDGES) return;
  int f = flag[0];
  int r = edge_row(ei, e, f);
  int c = edge_col(ei, e, f);
  int p = atomicAdd(&fillpos[c], 1);
  float w = dinv[r] * dinv[c];
  ep[p] = make_int2(r, __builtin_bit_cast(int, w));
}

// ---------------- weight prep: fp32 [in][out] -> bf16 transposed [out][in] --
__global__ void prep_w_kernel(const float* __restrict__ W0, const float* __restrict__ W1,
                              const float* __restrict__ W2, unsigned short* __restrict__ Wt) {
  int id = blockIdx.x * blockDim.x + threadIdx.x;
  if (id >= 3 * DD * DD) return;
  int mat = id / (DD * DD);
  int rem = id % (DD * DD);
  int k = rem / DD;  // in
  int n = rem % DD;  // out
  const float* W = (mat == 0) ? W0 : (mat == 1) ? W1 : W2;
  Wt[mat * DD * DD + n * DD + k] = f2bf(W[k * DD + n]);
}

// ---------------- MHA prep: W' = Wv@Wo (bf16, transposed), bias' = bv@Wo+bo --
__global__ void prep_mha_kernel(const float* __restrict__ Wv, const float* __restrict__ Wo,
                                const float* __restrict__ bv, const float* __restrict__ bo,
                                unsigned short* __restrict__ Wt5, float* __restrict__ biasp) {
  int id = blockIdx.x * blockDim.x + threadIdx.x;
  if (id < DD * DD) {
    int k = id >> 7, n = id & 127;
    float acc = 0.f;
    for (int j = 0; j < DD; ++j) acc += Wv[k * DD + j] * Wo[j * DD + n];
    Wt5[n * DD + k] = f2bf(acc);  // transposed [out][in]
  } else if (id < DD * DD + DD) {
    int n = id - DD * DD;
    float acc = bo[n];
    for (int j = 0; j < DD; ++j) acc += bv[j] * Wo[j * DD + n];
    biasp[n] = acc;
  }
}

// ---------------- bf16 MFMA GEMM -> bf16 C:  C[N,128] = A[N,128] @ W (+bias)
template <typename AT>
__global__ __launch_bounds__(256) void gemm_bf16_kernel(const AT* __restrict__ A,
                                                        const unsigned short* __restrict__ Wt,
                                                        const float* __restrict__ bias,
                                                        unsigned short* __restrict__ C) {
  __shared__ short As[128][136];  // +8 pad: breaks bank conflicts on frag reads
  __shared__ short Ws[128][136];
  const int tid = threadIdx.x;
  const int rowbase = blockIdx.x * 128;

#pragma unroll
  for (int i = 0; i < 8; ++i) {
    int ch = tid + i * 256;  // 2048 chunks of 8 shorts
    int r = ch >> 4;
    int c = (ch & 15) << 3;
    int4 v = *(const int4*)(Wt + r * DD + c);
    *(int4*)(&Ws[r][c]) = v;
  }
  if constexpr (__is_same(AT, float)) {
#pragma unroll
    for (int i = 0; i < 16; ++i) {
      int ch = tid + i * 256;  // 4096 chunks of 4 floats
      int r = ch >> 5;
      int c = (ch & 31) << 2;
      int row = rowbase + r;
      float4 v = make_float4(0.f, 0.f, 0.f, 0.f);
      if (row < N_NODES) v = *(const float4*)(A + row * DD + c);
      short4v s;
      s.x = f2bf(v.x);
      s.y = f2bf(v.y);
      s.z = f2bf(v.z);
      s.w = f2bf(v.w);
      *(short4v*)(&As[r][c]) = s;
    }
  } else {
#pragma unroll
    for (int i = 0; i < 8; ++i) {
      int ch = tid + i * 256;
      int r = ch >> 4;
      int c = (ch & 15) << 3;
      int row = rowbase + r;
      int4 v = make_int4(0, 0, 0, 0);
      if (row < N_NODES) v = *(const int4*)(A + row * DD + c);
      *(int4*)(&As[r][c]) = v;
    }
  }
  __syncthreads();

  const int lane = tid & 63;
  const int wv = tid >> 6;
  const int m = lane & 15;
  const int q = lane >> 4;
  const int r0 = wv * 32;

  floatx4 acc[2][8];
#pragma unroll
  for (int t = 0; t < 2; ++t)
#pragma unroll
    for (int n = 0; n < 8; ++n) acc[t][n] = (floatx4){0.f, 0.f, 0.f, 0.f};

#pragma unroll
  for (int kc = 0; kc < 4; ++kc) {
    int k = kc * 32 + q * 8;
    short8 a0 = *(const short8*)(&As[r0 + m][k]);
    short8 a1 = *(const short8*)(&As[r0 + 16 + m][k]);
#pragma unroll
    for (int n = 0; n < 8; ++n) {
      short8 b = *(const short8*)(&Ws[n * 16 + m][k]);
      acc[0][n] = __builtin_amdgcn_mfma_f32_16x16x32_bf16(a0, b, acc[0][n], 0, 0, 0);
      acc[1][n] = __builtin_amdgcn_mfma_f32_16x16x32_bf16(a1, b, acc[1][n], 0, 0, 0);
    }
  }

  // epilogue: stage bf16 C tile in LDS (reuse As), coalesced 16B stores.
  // C/D layout col=lane&15, row=(lane>>4)*4+reg [measured m89/m91]
  __syncthreads();
#pragma unroll
  for (int n = 0; n < 8; ++n) {
    int col = n * 16 + m;
    float bvv = bias ? bias[col] : 0.f;
#pragma unroll
    for (int t = 0; t < 2; ++t) {
#pragma unroll
      for (int r = 0; r < 4; ++r) {
        int rl = r0 + t * 16 + q * 4 + r;
        As[rl][col] = (short)f2bf(acc[t][n][r] + bvv);
      }
    }
  }
  __syncthreads();
#pragma unroll
  for (int i = 0; i < 8; ++i) {
    int ch = tid + i * 256;
    int r = ch >> 4;
    int c = (ch & 15) << 3;
    int row = rowbase + r;
    if (row < N_NODES) *(int4*)(C + row * DD + c) = *(const int4*)(&As[r][c]);
  }
}

// ---------------- fused MHA+LN: h3 = LN(h2 + h2@W' + bias') -> bf16 ---------
__global__ __launch_bounds__(256) void gemm_mha_ln_kernel(
    const unsigned short* __restrict__ A, const unsigned short* __restrict__ Wt,
    const float* __restrict__ biasp, const float* __restrict__ lng,
    const float* __restrict__ lnb, unsigned short* __restrict__ C) {
  __shared__ short As[128][136];
  __shared__ short Ws[128][136];
  const int tid = threadIdx.x;
  const int rowbase = blockIdx.x * 128;

#pragma unroll
  for (int i = 0; i < 8; ++i) {
    int ch = tid + i * 256;
    int r = ch >> 4;
    int c = (ch & 15) << 3;
    int4 v = *(const int4*)(Wt + r * DD + c);
    *(int4*)(&Ws[r][c]) = v;
  }
#pragma unroll
  for (int i = 0; i < 8; ++i) {
    int ch = tid + i * 256;
    int r = ch >> 4;
    int c = (ch & 15) << 3;
    int row = rowbase + r;
    int4 v = make_int4(0, 0, 0, 0);
    if (row < N_NODES) v = *(const int4*)(A + row * DD + c);
    *(int4*)(&As[r][c]) = v;
  }
  __syncthreads();

  const int lane = tid & 63;
  const int wv = tid >> 6;
  const int m = lane & 15;
  const int q = lane >> 4;
  const int r0 = wv * 32;

  floatx4 acc[2][8];
#pragma unroll
  for (int t = 0; t < 2; ++t)
#pragma unroll
    for (int n = 0; n < 8; ++n) acc[t][n] = (floatx4){0.f, 0.f, 0.f, 0.f};

#pragma unroll
  for (int kc = 0; kc < 4; ++kc) {
    int k = kc * 32 + q * 8;
    short8 a0 = *(const short8*)(&As[r0 + m][k]);
    short8 a1 = *(const short8*)(&As[r0 + 16 + m][k]);
#pragma unroll
    for (int n = 0; n < 8; ++n) {
      short8 b = *(const short8*)(&Ws[n * 16 + m][k]);
      acc[0][n] = __builtin_amdgcn_mfma_f32_16x16x32_bf16(a0, b, acc[0][n], 0, 0, 0);
      acc[1][n] = __builtin_amdgcn_mfma_f32_16x16x32_bf16(a1, b, acc[1][n], 0, 0, 0);
    }
  }
  __syncthreads();  // everyone done reading Ws; As kept (residual source)

  float bp[8], gg[8], bb[8];
#pragma unroll
  for (int n = 0; n < 8; ++n) {
    int col = n * 16 + m;
    bp[n] = biasp[col];
    gg[n] = lng[col];
    bb[n] = lnb[col];
  }

#pragma unroll
  for (int t = 0; t < 2; ++t) {
#pragma unroll
    for (int r = 0; r < 4; ++r) {
      int rl = r0 + t * 16 + q * 4 + r;
      float v[8];
      float s = 0.f, ss = 0.f;
#pragma unroll
      for (int n = 0; n < 8; ++n) {
        float val = acc[t][n][r] + bp[n] + bf2f((unsigned short)As[rl][n * 16 + m]);
        v[n] = val;
        s += val;
        ss += val * val;
      }
      // row reduce across the 16 lanes sharing q (xor of lane bits 0..3)
#pragma unroll
      for (int o = 1; o <= 8; o <<= 1) {
        s += __shfl_xor(s, o, 64);
        ss += __shfl_xor(ss, o, 64);
      }
      float mu = s * (1.f / 128.f);
      float var = ss * (1.f / 128.f) - mu * mu;
      float rs = rsqrtf(var + EPS_LN);
#pragma unroll
      for (int n = 0; n < 8; ++n) {
        Ws[rl][n * 16 + m] = (short)f2bf((v[n] - mu) * rs * gg[n] + bb[n]);
      }
    }
  }
  __syncthreads();
#pragma unroll
  for (int i = 0; i < 8; ++i) {
    int ch = tid + i * 256;
    int r = ch >> 4;
    int c = (ch & 15) << 3;
    int row = rowbase + r;
    if (row < N_NODES) *(int4*)(C + row * DD + c) = *(const int4*)(&Ws[r][c]);
  }
}

// ---------------- sparse aggregate (bf16 gather, fp32 out) ------------------
// out[n] = sum_{e: col=n} w_e * hW[src_e] + d2[n]*hW[n] + b
__global__ __launch_bounds__(256) void aggregate_kernel(const unsigned* __restrict__ hw,
                                                        const int2* __restrict__ ep,
                                                        const int* __restrict__ off,
                                                        const float* __restrict__ d2,
                                                        const float* __restrict__ bias,
                                                        float* __restrict__ out) {
  int node = (blockIdx.x * blockDim.x + threadIdx.x) >> 6;
  int lane = threadIdx.x & 63;
  if (node >= N_NODES) return;
  node = __builtin_amdgcn_readfirstlane(node);  // force scalar edge-list walk
  int s = off[node], e = off[node + 1];
  float ax = 0.f, ay = 0.f;
  int p = s;
  for (; p + 7 < e; p += 8) {  // 8 outstanding gathers per wave
    int2 e0 = ep[p], e1 = ep[p + 1], e2 = ep[p + 2], e3 = ep[p + 3];
    int2 e4 = ep[p + 4], e5 = ep[p + 5], e6 = ep[p + 6], e7 = ep[p + 7];
    unsigned u0 = hw[e0.x * 64 + lane];
    unsigned u1 = hw[e1.x * 64 + lane];
    unsigned u2 = hw[e2.x * 64 + lane];
    unsigned u3 = hw[e3.x * 64 + lane];
    unsigned u4 = hw[e4.x * 64 + lane];
    unsigned u5 = hw[e5.x * 64 + lane];
    unsigned u6 = hw[e6.x * 64 + lane];
    unsigned u7 = hw[e7.x * 64 + lane];
    float w0 = __builtin_bit_cast(float, e0.y), w1 = __builtin_bit_cast(float, e1.y);
    float w2 = __builtin_bit_cast(float, e2.y), w3 = __builtin_bit_cast(float, e3.y);
    float w4 = __builtin_bit_cast(float, e4.y), w5 = __builtin_bit_cast(float, e5.y);
    float w6 = __builtin_bit_cast(float, e6.y), w7 = __builtin_bit_cast(float, e7.y);
    ax += w0 * bflo(u0);
    ay += w0 * bfhi(u0);
    ax += w1 * bflo(u1);
    ay += w1 * bfhi(u1);
    ax += w2 * bflo(u2);
    ay += w2 * bfhi(u2);
    ax += w3 * bflo(u3);
    ay += w3 * bfhi(u3);
    ax += w4 * bflo(u4);
    ay += w4 * bfhi(u4);
    ax += w5 * bflo(u5);
    ay += w5 * bfhi(u5);
    ax += w6 * bflo(u6);
    ay += w6 * bfhi(u6);
    ax += w7 * bflo(u7);
    ay += w7 * bfhi(u7);
  }
  for (; p < e; ++p) {
    int2 ee = ep[p];
    float w = __builtin_bit_cast(float, ee.y);
    unsigned u = hw[ee.x * 64 + lane];
    ax += w * bflo(u);
    ay += w * bfhi(u);
  }
  float sw = d2[node];
  unsigned uh = hw[node * 64 + lane];
  float2 b = ((const float2*)bias)[lane];
  float2 o;
  o.x = ax + sw * bflo(uh) + b.x;
  o.y = ay + sw * bfhi(uh) + b.y;
  ((float2*)out)[node * 64 + lane] = o;
}

// ---------------- BN stats (per-feature sum, sumsq over nodes) --------------
__global__ void bn_stats_kernel(const float* __restrict__ in, float* __restrict__ sum,
                                float* __restrict__ sumsq) {
  int col = threadIdx.x;  // 128 threads
  float s = 0.f, ss = 0.f;
  for (int r = blockIdx.x; r < N_NODES; r += gridDim.x) {
    float v = in[r * DD + col];
    s += v;
    ss += v * v;
  }
  atomicAdd(&sum[col], s);
  atomicAdd(&sumsq[col], ss);
}

// ---------------- BN normalize + ReLU + residual -> bf16 --------------------
template <typename RT>
__global__ void bn_norm_kernel(const float* __restrict__ in, const float* __restrict__ sum,
                               const float* __restrict__ sumsq, const float* __restrict__ g,
                               const float* __restrict__ be, const RT* __restrict__ res,
                               unsigned short* __restrict__ out) {
  int idx = blockIdx.x * blockDim.x + threadIdx.x;  // over N*32 groups of 4 cols
  if (idx >= N_NODES * 32) return;
  int c4 = (idx & 31) << 2;
  float4 v = ((const float4*)in)[idx];
  float r4[4];
  if constexpr (__is_same(RT, float)) {
    float4 r = ((const float4*)res)[idx];
    r4[0] = r.x; r4[1] = r.y; r4[2] = r.z; r4[3] = r.w;
  } else {
    short4v r = ((const short4v*)res)[idx];
    r4[0] = bf2f((unsigned short)r.x);
    r4[1] = bf2f((unsigned short)r.y);
    r4[2] = bf2f((unsigned short)r.z);
    r4[3] = bf2f((unsigned short)r.w);
  }
  const float invn = 1.0f / (float)N_NODES;
  short4v o;
#pragma unroll
  for (int j = 0; j < 4; ++j) {
    int c = c4 + j;
    float mu = sum[c] * invn;
    float var = sumsq[c] * invn - mu * mu;
    float sc = g[c] * rsqrtf(var + EPS_BN);
    float x = ((const float*)&v)[j];
    float y = (x - mu) * sc + be[c];
    y = fmaxf(y, 0.f) + r4[j];
    ((short*)&o)[j] = (short)f2bf(y);
  }
  ((short4v*)out)[idx] = o;
}

extern "C" void kernel_launch(void* const* d_in, const int* in_sizes, int n_in,
                              void* d_out, int out_size, void* d_ws, size_t ws_size,
                              hipStream_t stream) {
  const float* x = (const float*)d_in[0];
  const int* ei = (const int*)d_in[1];
  const float* W0 = (const float*)d_in[2];
  const float* b0 = (const float*)d_in[3];
  const float* W1 = (const float*)d_in[4];
  const float* b1 = (const float*)d_in[5];
  const float* W2 = (const float*)d_in[6];
  const float* b2 = (const float*)d_in[7];
  const float* g0 = (const float*)d_in[8];
  const float* be0 = (const float*)d_in[9];
  const float* g1 = (const float*)d_in[10];
  const float* be1 = (const float*)d_in[11];
  const float* Wv = (const float*)d_in[12];
  const float* bv = (const float*)d_in[13];
  const float* Wo = (const float*)d_in[14];
  const float* bo = (const float*)d_in[15];
  const float* lng = (const float*)d_in[16];
  const float* lnb = (const float*)d_in[17];
  float* outp = (float*)d_out;

  char* w = (char*)d_ws;
  unsigned short* Gb = (unsigned short*)(w + 0);          // 25,600,000 B (hW / V)
  unsigned short* h1b = (unsigned short*)(w + 25600000);  // 25,600,000 B (h1, later h3)
  unsigned short* h2b = (unsigned short*)(w + 51200000);  // 25,600,000 B (h2)
  int2* ep = (int2*)(w + 76800000);                       // 12,800,000 B (src+weight)
  int* cnt = (int*)(w + 89600000);                        // 400,000 B
  int* off = (int*)(w + 90000000);                        // 400,004 B (pad)
  int* fillpos = (int*)(w + 90400256);                    // 400,000 B
  float* dinv = (float*)(w + 90800256);                   // 400,000 B
  float* d2v = (float*)(w + 91200256);                    // 400,000 B
  int* blksum = (int*)(w + 91600256);                     // 512 B
  float* sums = (float*)(w + 91600768);                   // 2,048 B
  unsigned short* Wt = (unsigned short*)(w + 91602816);   // 4 mats: 131,072 B
  unsigned short* Wt5 = Wt + 3 * DD * DD;                 // W' slot
  float* biasp = (float*)(w + 91733888);                  // 512 B
  int* flag = (int*)(w + 91734400);                       // 4 B
  float* outF = outp;  // d_out doubles as the fp32 scratch (aggregate out)

  // --- precompute: edge dtype, degrees, CSR(+weights), weight matrices ---
  detect_kernel<<<1, 1024, 0, stream>>>(ei, flag);
  init_kernel<<<(N_NODES + 255) / 256, 256, 0, stream>>>(cnt, sums);
  count_kernel<<<(N_EDGES + 255) / 256, 256, 0, stream>>>(ei, flag, cnt);
  dinv_kernel<<<(N_NODES + 255) / 256, 256, 0, stream>>>(cnt, dinv, d2v);
  scan_block_kernel<<<NBLK, SCAN_B, 0, stream>>>(cnt, off, blksum);
  scan_tops_kernel<<<1, SCAN_B, 0, stream>>>(blksum);
  scan_add_kernel<<<NBLK, SCAN_B, 0, stream>>>(off, fillpos, blksum);
  fill_kernel<<<(N_EDGES + 255) / 256, 256, 0, stream>>>(ei, flag, dinv, fillpos, ep);
  prep_w_kernel<<<(3 * DD * DD + 255) / 256, 256, 0, stream>>>(W0, W1, W2, Wt);
  prep_mha_kernel<<<(DD * DD + DD + 255) / 256, 256, 0, stream>>>(Wv, Wo, bv, bo, Wt5, biasp);

  const int GB = (N_NODES + 127) / 128;  // 782 gemm blocks
  const int AB = (N_NODES + 3) / 4;      // 25000 blocks (4 waves/block, 1 wave/node)
  const int EB = (N_NODES * 32 + 255) / 256;

  // --- layer 0: conv -> BN -> relu -> +x ---
  gemm_bf16_kernel<float><<<GB, 256, 0, stream>>>(x, Wt + 0 * DD * DD, nullptr, Gb);
  aggregate_kernel<<<AB, 256, 0, stream>>>((const unsigned*)Gb, ep, off, d2v, b0, outF);
  bn_stats_kernel<<<512, 128, 0, stream>>>(outF, sums + 0, sums + 128);
  bn_norm_kernel<float><<<EB, 256, 0, stream>>>(outF, sums + 0, sums + 128, g0, be0, x, h1b);

  // --- layer 1 ---
  gemm_bf16_kernel<unsigned short><<<GB, 256, 0, stream>>>(h1b, Wt + 1 * DD * DD, nullptr, Gb);
  aggregate_kernel<<<AB, 256, 0, stream>>>((const unsigned*)Gb, ep, off, d2v, b1, outF);
  bn_stats_kernel<<<512, 128, 0, stream>>>(outF, sums + 256, sums + 384);
  bn_norm_kernel<unsigned short><<<EB, 256, 0, stream>>>(outF, sums + 256, sums + 384, g1, be1,
                                                         h1b, h2b);

  // --- MHA (seq_len=1) + LN fused into ONE GEMM: h3 = LN(h2 + h2@W' + bias')
  gemm_mha_ln_kernel<<<GB, 256, 0, stream>>>(h2b, Wt5, biasp, lng, lnb, h1b);  // h3 -> h1b

  // --- output conv ---
  gemm_bf16_kernel<unsigned short><<<GB, 256, 0, stream>>>(h1b, Wt + 2 * DD * DD, nullptr, Gb);
  aggregate_kernel<<<AB, 256, 0, stream>>>((const unsigned*)Gb, ep, off, d2v, b2, outp);
}